// Round 5
// baseline (480.382 us; speedup 1.0000x reference)
//
#include <hip/hip_runtime.h>
#include <math.h>

// Problem constants
#define NPIX   131072      // 32*64*64 pixels
#define KCODES 512
#define DIM    64
#define HW     4096        // 64*64
#define CHW    262144      // 64*4096
#define NBLK   2048        // 64 px per block

// Output layout (floats, concatenated in reference return order)
#define O_Q    1ll
#define O_PERP 8388609ll
#define O_ENC  8388610ll
#define O_IDX  75497474ll

// ws layout (floats): [0] loss accum, [1..512] counts (u32), [513..1024] esq

// Replicate numpy pairwise_sum of x**2 for n=64 (8 accs, stride-8, pairwise combine).
__device__ __forceinline__ float np_sumsq64(const float (&x)[64]) {
#pragma clang fp contract(off)
  float r0 = x[0]*x[0], r1 = x[1]*x[1], r2 = x[2]*x[2], r3 = x[3]*x[3];
  float r4 = x[4]*x[4], r5 = x[5]*x[5], r6 = x[6]*x[6], r7 = x[7]*x[7];
#pragma unroll
  for (int i = 8; i < 64; i += 8) {
    r0 += x[i+0]*x[i+0];
    r1 += x[i+1]*x[i+1];
    r2 += x[i+2]*x[i+2];
    r3 += x[i+3]*x[i+3];
    r4 += x[i+4]*x[i+4];
    r5 += x[i+5]*x[i+5];
    r6 += x[i+6]*x[i+6];
    r7 += x[i+7]*x[i+7];
  }
  return ((r0+r1)+(r2+r3))+((r4+r5)+(r6+r7));
}

// Prep: zero loss accumulator + counts, compute esq[k] (np-pairwise) into ws.
__global__ void vq_prep(const float* __restrict__ emb, float* __restrict__ ws) {
  const int t = threadIdx.x;  // 512 threads
  if (t == 0) ws[0] = 0.0f;
  ((unsigned*)ws)[1 + t] = 0u;
  float x[64];
  const float* e = emb + t * DIM;
#pragma unroll
  for (int d = 0; d < 64; ++d) x[d] = e[d];
  ws[513 + t] = np_sumsq64(x);
}

// Main: round-12 wave-per-px-group remap (LDS traffic halved).
// Geometry: block = 512 threads = 8 waves; each WAVE owns 8 pixels x all 512
// codes (lane ci owns codes 8ci..8ci+7); block = 64 px; grid = 2048.
// Why: r0-r4 were LDS-pipe-bound (~82us device floor: 4 ds_read_b128 per
// 64 FMAs). With the wave owning one px-group, the z operand is WAVE-UNIFORM
// -> loaded as a broadcast float4 pair straight from global (single L1
// request per instr; 16KB z tile is L1-resident after the zsq pass). z never
// touches LDS; LDS carries only the ET slice (lane reads 8 contiguous codes
// = 2 conflict-free b128/dl). LDS-read floor halves to ~41us; VALU (~75us)
// becomes the binding pipe. 16-dim double-buffered ET slices -> only 4
// in-loop barriers. Enc zeros + quantized use nontemporal stores so the
// 268MB stream doesn't thrash the 4MB XCD L2s.
// Occupancy: VGPR-capped 4 waves/SIMD (launch_bounds <=128) -> 16 waves/CU
// = 2 blocks/CU; LDS 70.2KB also 2/CU; 2048 blocks = 4 perfectly-packed
// rounds (no fractional tail).
// Exactness (np.argmin bit-identical): per-(px,k) fmaf chain d=0..63
// ascending in ONE chain; dist = (zsq+esq)-2*acc; per-lane scan r ascending
// (= k ascending), strict <; butterfly masks 32..1 tie-breaks to lower k;
// zsq via per-residue partials (ascending m, contract off) + the exact
// np pairwise combine.
__global__ __launch_bounds__(512, 4)
void vq_main(
    const float* __restrict__ z, const float* __restrict__ emb,
    float* __restrict__ out, float* __restrict__ ws)
{
  __shared__ float ET_s[2][16 * 512];  // 64KB: double-buffered 16-d ET slices
  __shared__ float esq_l[512];
  __shared__ float zsqp[512];          // [j][px] partial sums (j = residue)
  __shared__ float zsq_l[64];
  __shared__ int   ridx_l[64];
  __shared__ float wsum[8];

  const int t    = threadIdx.x;      // 0..511
  const int lane = t & 63;           // lane within wave = code group ci
  const int wv   = t >> 6;           // 0..7: wave = px group
  const int blk  = blockIdx.x;       // grid = 2048
  const int n0   = blk * 64;         // 64 consecutive pixels (same batch b)
  const int b    = n0 >> 12;
  const int hw0  = n0 & 4095;
  const float* zg = z + (size_t)b * CHW + hw0;

  esq_l[t] = ws[513 + t];

  // zsq partials: thread (j=wv residue, px=lane): r_j = sum_m z[8m+j][px]^2,
  // m ascending, mul+add (no fma) — exactly np_sumsq64's per-accumulator sum.
  {
#pragma clang fp contract(off)
    float r = 0.0f;
#pragma unroll
    for (int m = 0; m < 8; ++m) {
      const float x = zg[(size_t)(8 * m + wv) * HW + lane];
      r += x * x;
    }
    zsqp[t] = r;   // zsqp[wv*64 + lane]
  }

  // ET staging mapping: thread covers codes {2tc, 2tc+1}, dls 8th..8th+7.
  const int tc = t & 255;
  const int th = t >> 8;
  float pa[8], pb[8];
  {  // prefetch slice 0
    const float* ea = emb + (size_t)(2 * tc) * 64 + 8 * th;
    const float* eb = ea + 64;
#pragma unroll
    for (int i = 0; i < 8; ++i) { pa[i] = ea[i]; pb[i] = eb[i]; }
  }
  {  // write slice 0 -> buf0 (b64 code-pair stores, conflict-free)
#pragma unroll
    for (int i = 0; i < 8; ++i)
      *(float2*)&ET_s[0][(8 * th + i) * 512 + 2 * tc] = make_float2(pa[i], pb[i]);
  }
  {  // prefetch slice 1
    const float* ea = emb + (size_t)(2 * tc) * 64 + 16 + 8 * th;
    const float* eb = ea + 64;
#pragma unroll
    for (int i = 0; i < 8; ++i) { pa[i] = ea[i]; pb[i] = eb[i]; }
  }

  __syncthreads();   // B0: esq_l, zsqp, ET buf0 ready

  float bd[8];
  int   bk[8];
#pragma unroll
  for (int j = 0; j < 8; ++j) { bd[j] = INFINITY; bk[j] = 0; }
  float acc[8][8];   // [px j][code r]
#pragma unroll
  for (int j = 0; j < 8; ++j)
#pragma unroll
    for (int c = 0; c < 8; ++c) acc[j][c] = 0.0f;

  double* encd = (double*)(out + O_ENC) + (size_t)n0 * 256;  // 8B-aligned

  // Main loop: 4 slices of 16 dims, one barrier each.
  // Body g: write slice g+1 (regs prefetched in body g-1) into buf[(g+1)&1],
  // prefetch slice g+2, stream enc zeros (NT), FMA on buf[g&1].
  for (int g = 0; g < 4; ++g) {
    if (g < 3) {
#pragma unroll
      for (int i = 0; i < 8; ++i)
        *(float2*)&ET_s[(g + 1) & 1][(8 * th + i) * 512 + 2 * tc] =
            make_float2(pa[i], pb[i]);
    }
    if (g < 2) {
      const float* ea = emb + (size_t)(2 * tc) * 64 + 16 * (g + 2) + 8 * th;
      const float* eb = ea + 64;
#pragma unroll
      for (int i = 0; i < 8; ++i) { pa[i] = ea[i]; pb[i] = eb[i]; }
    }
    // enc zeros: 8 NT doubles/thread/slice; drained by this body's barrier.
#pragma unroll
    for (int u = 0; u < 8; ++u)
      __builtin_nontemporal_store(0.0, encd + (size_t)g * 4096 + u * 512 + t);
    // zsq final combine (exact np pairwise), published by body-0 barrier.
    if (g == 0 && t < 64) {
      zsq_l[t] = ((zsqp[t] + zsqp[64 + t]) + (zsqp[128 + t] + zsqp[192 + t])) +
                 ((zsqp[256 + t] + zsqp[320 + t]) + (zsqp[384 + t] + zsqp[448 + t]));
    }

    const float* ETb = &ET_s[g & 1][0];
#pragma unroll 2
    for (int dl = 0; dl < 16; ++dl) {
      // z operand: wave-uniform broadcast from global (L1-resident tile).
      const float* zrow = zg + (size_t)(16 * g + dl) * HW + 8 * wv;
      const float4 za0 = *(const float4*)(zrow + 0);
      const float4 za1 = *(const float4*)(zrow + 4);
      // e operand: 8 contiguous codes for this lane, conflict-free b128 pair.
      const float* ep = &ETb[dl * 512 + 8 * lane];
      const float4 e0 = *(const float4*)(ep + 0);
      const float4 e1 = *(const float4*)(ep + 4);
      const float zr[8] = {za0.x, za0.y, za0.z, za0.w,
                           za1.x, za1.y, za1.z, za1.w};
      const float er[8] = {e0.x, e0.y, e0.z, e0.w,
                           e1.x, e1.y, e1.z, e1.w};
#pragma unroll
      for (int j = 0; j < 8; ++j)
#pragma unroll
        for (int c = 0; c < 8; ++c)
          acc[j][c] = fmaf(zr[j], er[c], acc[j][c]);
    }
    __syncthreads();
  }

  // dist + argmin: lane's codes k = 8*lane + r, r ascending = k ascending.
  {
    const float4 q0 = *(const float4*)&esq_l[8 * lane];
    const float4 q1 = *(const float4*)&esq_l[8 * lane + 4];
    const float eqs[8] = {q0.x, q0.y, q0.z, q0.w, q1.x, q1.y, q1.z, q1.w};
#pragma unroll
    for (int r = 0; r < 8; ++r) {
      const int k = 8 * lane + r;
#pragma unroll
      for (int j = 0; j < 8; ++j) {
        const float dist = (zsq_l[8 * wv + j] + eqs[r]) - 2.0f * acc[j][r];
        if (dist < bd[j]) { bd[j] = dist; bk[j] = k; }
      }
    }
  }

  // Butterfly merge across all 64 lanes (tie-break: lower k), exact.
#pragma unroll
  for (int m = 32; m >= 1; m >>= 1) {
#pragma unroll
    for (int j = 0; j < 8; ++j) {
      const float od = __shfl_xor(bd[j], m, 64);
      const int   ok = __shfl_xor(bk[j], m, 64);
      if (od < bd[j] || (od == bd[j] && ok < bk[j])) { bd[j] = od; bk[j] = ok; }
    }
  }
  if (lane == 0) {
#pragma unroll
    for (int j = 0; j < 8; ++j) ridx_l[8 * wv + j] = bk[j];
  }
  __syncthreads();  // publishes ridx_l (enc zeros drained at loop barriers)

  // ---- epilogue ----
  if (t < 64) {
    const int k = ridx_l[t];
    out[O_IDX + n0 + t] = (float)k;
    atomicAdd((unsigned*)ws + 1 + k, 1u);
    // One-hot scatter: zeros at this row are already globally complete.
    out[O_ENC + (size_t)(n0 + t) * 512 + k] = 1.0f;
  }

  // quantized + loss: thread (px=lane, dq=wv) handles 8 d's of one pixel.
  {
    const int px = lane;
    const int k  = ridx_l[px];
    const float* e0 = emb + ((size_t)k << 6);
    float* q0 = out + O_Q + (size_t)b * CHW + hw0 + px;
    float lsum = 0.0f;
#pragma unroll
    for (int j = 0; j < 8; ++j) {
      const int d = 8 * wv + j;
      const float ev = e0[d];
      const float df = ev - zg[(size_t)d * HW + px];
      lsum = fmaf(df, df, lsum);
      __builtin_nontemporal_store(ev, q0 + (size_t)d * HW);
    }
#pragma unroll
    for (int off = 32; off > 0; off >>= 1) lsum += __shfl_down(lsum, off, 64);
    if (lane == 0) wsum[wv] = lsum;
  }
  __syncthreads();
  if (t == 0)
    atomicAdd(ws, ((wsum[0] + wsum[1]) + (wsum[2] + wsum[3])) +
                  ((wsum[4] + wsum[5]) + (wsum[6] + wsum[7])));
}

// Finalize: perplexity from counts (exact: counts/2^17), loss mean.
__global__ void vq_fin(float* __restrict__ out, const float* __restrict__ ws) {
  __shared__ float red[8];
  const int t = threadIdx.x;  // 512
  const unsigned* counts = (const unsigned*)ws + 1;
  const float p = (float)counts[t] * (1.0f / 131072.0f);
  float h = p * logf(p + 1e-10f);
#pragma unroll
  for (int off = 32; off > 0; off >>= 1) h += __shfl_down(h, off, 64);
  if ((t & 63) == 0) red[t >> 6] = h;
  __syncthreads();
  if (t == 0) {
    float H = 0.0f;
#pragma unroll
    for (int w = 0; w < 8; ++w) H += red[w];
    out[O_PERP] = expf(-H);
    out[0] = 1.25f * ws[0] * (1.0f / 8388608.0f);
  }
}

extern "C" void kernel_launch(void* const* d_in, const int* in_sizes, int n_in,
                              void* d_out, int out_size, void* d_ws, size_t ws_size,
                              hipStream_t stream) {
  const float* z   = (const float*)d_in[0];
  const float* emb = (const float*)d_in[1];
  float* out = (float*)d_out;
  float* ws  = (float*)d_ws;

  vq_prep<<<1, 512, 0, stream>>>(emb, ws);
  vq_main<<<NBLK, 512, 0, stream>>>(z, emb, out, ws);
  vq_fin<<<1, 512, 0, stream>>>(out, ws);
}